// Round 7
// baseline (941.695 us; speedup 1.0000x reference)
//
#include <hip/hip_runtime.h>
#include <hip/hip_bf16.h>
#include <math.h>

#define B_  256
#define S_  200
#define F_  10
#define T_  100
#define E_  128
#define H_  256
#define G4  1024   // 4*H
#define P1_ 512
#define P2_ 128

typedef __attribute__((ext_vector_type(8))) short short8;
typedef __attribute__((ext_vector_type(4))) float f32x4;
typedef _Float16 half2f __attribute__((ext_vector_type(2)));

#if __has_builtin(__builtin_amdgcn_fdot2)
#define FDOT2(w2, h2, acc) __builtin_amdgcn_fdot2((w2), (h2), (acc), false)
#else
#define FDOT2(w2, h2, acc) ((acc) + (float)((w2)[0]) * (float)((h2)[0]) + (float)((w2)[1]) * (float)((h2)[1]))
#endif

__device__ __forceinline__ float sigf(float x) { return 1.0f / (1.0f + expf(-x)); }
__device__ __forceinline__ ushort f2bf(float f) {
    __hip_bfloat16 v = __float2bfloat16(f);
    return *(ushort*)&v;
}
__device__ __forceinline__ ushort f2h(float f) {
    _Float16 h = (_Float16)f;
    return __builtin_bit_cast(ushort, h);
}

__global__ __launch_bounds__(256) void k_bsum(const float* __restrict__ bi,
                                              const float* __restrict__ bh,
                                              float* __restrict__ bs) {
    int i = blockIdx.x * 256 + threadIdx.x;
    if (i < G4) bs[i] = bi[i] + bh[i];
}

// W (R x C) f32 -> WT (C x R) bf16. grid (C/32, R/32), 256 thr.
__global__ __launch_bounds__(256) void k_tr_bf16(const float* __restrict__ W,
                                                 ushort* __restrict__ WT,
                                                 int R, int C) {
    __shared__ float t[32][33];
    int c0 = blockIdx.x * 32, r0 = blockIdx.y * 32;
    int lc = threadIdx.x & 31, lr = threadIdx.x >> 5;
    #pragma unroll
    for (int i = 0; i < 4; ++i)
        t[lr + 8 * i][lc] = W[(long)(r0 + lr + 8 * i) * C + c0 + lc];
    __syncthreads();
    #pragma unroll
    for (int i = 0; i < 4; ++i)
        WT[(long)(c0 + lr + 8 * i) * R + r0 + lc] = f2bf(t[lc][lr + 8 * i]);
}

// W_hh (1024 x 256) f32 -> WPu: k-pair-interleaved fp16.
// WPu[kp*1024 + c] = pack(f16(W[c][2kp]), f16(W[c][2kp+1])), kp=0..127.
__global__ __launch_bounds__(256) void k_prep_wp(const float* __restrict__ W,
                                                 uint* __restrict__ WPu) {
    __shared__ float t[32][33];
    int k0 = blockIdx.x * 32, c0 = blockIdx.y * 32;
    int lk = threadIdx.x & 31, lc8 = threadIdx.x >> 5;
    #pragma unroll
    for (int i = 0; i < 4; ++i)
        t[lc8 + 8 * i][lk] = W[(long)(c0 + lc8 + 8 * i) * 256 + k0 + lk];
    __syncthreads();
    int kpl = threadIdx.x >> 4;   // 0..15
    int ccl = threadIdx.x & 15;   // 0..15
    #pragma unroll
    for (int hf = 0; hf < 2; ++hf) {
        int c = ccl + 16 * hf;
        uint lo = f2h(t[c][2 * kpl]);
        uint hi = f2h(t[c][2 * kpl + 1]);
        WPu[(long)(k0 / 2 + kpl) * G4 + c0 + c] = lo | (hi << 16);
    }
}

__global__ __launch_bounds__(256) void k_cvt_bf16(const float* __restrict__ W,
                                                  ushort* __restrict__ O, int n) {
    int i = blockIdx.x * 256 + threadIdx.x;
    if (i < n) O[i] = f2bf(W[i]);
}

// one block per (b,s); 128 threads = one e-dim each; bf16 out
__global__ __launch_bounds__(128) void k_gather(const int* __restrict__ x,
                                                const float* __restrict__ emb,
                                                ushort* __restrict__ e) {
    int bs = blockIdx.x;
    int t  = threadIdx.x;
    const int* xr = x + (long)bs * F_;
    float acc = 0.f;
    #pragma unroll
    for (int f = 0; f < F_; ++f) acc += emb[(long)xr[f] * E_ + t];
    e[(long)bs * E_ + t] = f2bf(acc * (1.0f / F_));
}

// ---------------- bf16 MFMA GEMM (unchanged) ----------------
template<int ACT, int OUTBF>
__global__ __launch_bounds__(256) void k_gemm_mfma(
    const ushort* __restrict__ A, int rowDiv, long sOuter, long sInner,
    const ushort* __restrict__ Bm,
    const float* __restrict__ bias,
    const float* __restrict__ rowAdd, int rowAddDiv,
    void* __restrict__ Cout, int N, int K)
{
    constexpr int LDT = 40;
    __shared__ ushort Al[128 * LDT];
    __shared__ ushort Bl[128 * LDT];
    int tid = threadIdx.x;
    int n0 = blockIdx.x * 128;
    int m0 = blockIdx.y * 128;

    int rA = tid >> 2, qA = tid & 3;
    int m_lo = m0 + rA, m_hi = m_lo + 64;
    long a0 = (long)(m_lo / rowDiv) * sOuter + (long)(m_lo % rowDiv) * sInner + qA * 8;
    long a1 = (long)(m_hi / rowDiv) * sOuter + (long)(m_hi % rowDiv) * sInner + qA * 8;
    const ushort* b0p = Bm + (long)(n0 + rA) * K + qA * 8;
    const ushort* b1p = Bm + (long)(n0 + rA + 64) * K + qA * 8;

    int lane = tid & 63, wave = tid >> 6;
    int wr = wave >> 1, wc = wave & 1;
    int lrow = lane & 15, lkh = lane >> 4;

    const f32x4 fz = {0.f, 0.f, 0.f, 0.f};
    f32x4 acc[4][4];
    #pragma unroll
    for (int i = 0; i < 4; ++i)
        #pragma unroll
        for (int j = 0; j < 4; ++j) acc[i][j] = fz;

    int nk = K >> 5;
    for (int kc = 0; kc < nk; ++kc) {
        uint4 va0 = *(const uint4*)(A + a0 + kc * 32);
        uint4 va1 = *(const uint4*)(A + a1 + kc * 32);
        uint4 vb0 = *(const uint4*)(b0p + kc * 32);
        uint4 vb1 = *(const uint4*)(b1p + kc * 32);
        *(uint4*)&Al[rA * LDT + qA * 8]        = va0;
        *(uint4*)&Al[(rA + 64) * LDT + qA * 8] = va1;
        *(uint4*)&Bl[rA * LDT + qA * 8]        = vb0;
        *(uint4*)&Bl[(rA + 64) * LDT + qA * 8] = vb1;
        __syncthreads();
        short8 af[4], bfr[4];
        #pragma unroll
        for (int mi = 0; mi < 4; ++mi)
            af[mi] = *(const short8*)&Al[(wr * 64 + mi * 16 + lrow) * LDT + lkh * 8];
        #pragma unroll
        for (int ni = 0; ni < 4; ++ni)
            bfr[ni] = *(const short8*)&Bl[(wc * 64 + ni * 16 + lrow) * LDT + lkh * 8];
        #pragma unroll
        for (int mi = 0; mi < 4; ++mi)
            #pragma unroll
            for (int ni = 0; ni < 4; ++ni)
                acc[mi][ni] = __builtin_amdgcn_mfma_f32_16x16x32_bf16(
                    af[mi], bfr[ni], acc[mi][ni], 0, 0, 0);
        __syncthreads();
    }
    #pragma unroll
    for (int mi = 0; mi < 4; ++mi) {
        #pragma unroll
        for (int r = 0; r < 4; ++r) {
            int m = m0 + wr * 64 + mi * 16 + lkh * 4 + r;
            long rowoff = rowAdd ? (long)(m / rowAddDiv) * N : 0;
            #pragma unroll
            for (int ni = 0; ni < 4; ++ni) {
                int n = n0 + wc * 64 + ni * 16 + lrow;
                float v = acc[mi][ni][r];
                if (bias)   v += bias[n];
                if (rowAdd) v += rowAdd[rowoff + n];
                if (ACT)    v = fmaxf(v, 0.f);
                if (OUTBF) ((ushort*)Cout)[(long)m * N + n] = f2bf(v);
                else       ((float*)Cout)[(long)m * N + n] = v;
            }
        }
    }
}

// ---------------- fp32 GEMM (kept for small hhdec) ----------------
template<int BT, int ACT>
__global__ __launch_bounds__(256) void k_gemm(
    const float* __restrict__ A, int rowDiv, long sOuter, long sInner,
    const float* __restrict__ Bm,
    const float* __restrict__ bias,
    const float* __restrict__ rowAdd, int rowAddDiv,
    float* __restrict__ C, int M, int N, int K)
{
    __shared__ float Al[32 * 66];
    __shared__ float Bl[32 * 130];
    int tid = threadIdx.x;
    int n0 = blockIdx.x * 128;
    int m0 = blockIdx.y * 64;
    int cA = tid & 31;
    int rA = tid >> 5;
    long rb[8];
    #pragma unroll
    for (int i = 0; i < 8; ++i) {
        int m = m0 + rA + 8 * i;
        rb[i] = (long)(m / rowDiv) * sOuter + (long)(m % rowDiv) * sInner;
    }
    int tr = tid >> 5, tc = tid & 31;
    float acc[8][4] = {};
    int nk = K >> 5;
    for (int kc = 0; kc < nk; ++kc) {
        #pragma unroll
        for (int i = 0; i < 8; ++i)
            Al[cA * 66 + rA + 8 * i] = A[rb[i] + kc * 32 + cA];
        if (BT) {
            #pragma unroll
            for (int i = 0; i < 16; ++i) {
                int lin = tid + 256 * i;
                int n = lin >> 5, k = lin & 31;
                Bl[k * 130 + n] = Bm[(long)(n0 + n) * K + kc * 32 + k];
            }
        } else {
            #pragma unroll
            for (int i = 0; i < 16; ++i) {
                int lin = tid + 256 * i;
                int k = lin >> 7, n = lin & 127;
                Bl[k * 130 + n] = Bm[(long)(kc * 32 + k) * N + n0 + n];
            }
        }
        __syncthreads();
        #pragma unroll 4
        for (int k = 0; k < 32; ++k) {
            float a_[8], b_[4];
            *(float2*)&a_[0] = *(float2*)&Al[k * 66 + tr * 8];
            *(float2*)&a_[2] = *(float2*)&Al[k * 66 + tr * 8 + 2];
            *(float2*)&a_[4] = *(float2*)&Al[k * 66 + tr * 8 + 4];
            *(float2*)&a_[6] = *(float2*)&Al[k * 66 + tr * 8 + 6];
            *(float2*)&b_[0] = *(float2*)&Bl[k * 130 + tc * 4];
            *(float2*)&b_[2] = *(float2*)&Bl[k * 130 + tc * 4 + 2];
            #pragma unroll
            for (int i = 0; i < 8; ++i)
                #pragma unroll
                for (int j = 0; j < 4; ++j)
                    acc[i][j] += a_[i] * b_[j];
        }
        __syncthreads();
    }
    #pragma unroll
    for (int i = 0; i < 8; ++i) {
        int m = m0 + tr * 8 + i;
        int n = n0 + tc * 4;
        float4 v;
        float* vp = &v.x;
        #pragma unroll
        for (int j = 0; j < 4; ++j) {
            float t = acc[i][j];
            if (bias)   t += bias[n + j];
            if (rowAdd) t += rowAdd[(long)(m / rowAddDiv) * N + n + j];
            if (ACT == 1) t = fmaxf(t, 0.f);
            vp[j] = t;
        }
        *(float4*)&C[(long)m * N + n] = v;
    }
}

// Persistent batch-parallel LSTM scan: broadcast W stream + LDS W-cache + dot2.
// WPu: k-pair-interleaved fp16 W_hh^T (see k_prep_wp). One block per batch row.
// 1024 threads = 16 waves; wave w owns cols [w*64, w*64+64); lane = kg*8+cl,
// kg = k-group (32 k = 16 kpairs), cl -> 8 consecutive cols.
// First KC kpairs of W cached in LDS (loaded once); rest streamed from L2.
// k-partials reduced via 3-step shfl_xor butterfly over kg lanes.
#define KC_  32
#define LDW_ 2064   // 2048 halves + 16 pad
__global__ __launch_bounds__(1024) void k_lstm_scan(
    const float* __restrict__ Xg, const uint* __restrict__ WPu,
    float* __restrict__ hN, float* __restrict__ cN)
{
    extern __shared__ __align__(16) char smem[];
    ushort* Wl    = (ushort*)smem;                        // KC_*LDW_ halves
    float*  act_s = (float*)(smem + KC_ * LDW_ * 2);      // 1024 f32
    ushort* h_s16 = (ushort*)(act_s + G4);                // 256 f16
    int tid = threadIdx.x;
    int b   = blockIdx.x;

    // one-time W cache load (rows 0..KC_-1)
    for (int i = tid; i < KC_ * 1024; i += 1024) {
        int kp = i >> 10, c = i & 1023;
        ((uint*)(Wl + (size_t)kp * LDW_))[c] = WPu[(long)kp * G4 + c];
    }
    if (tid < H_) h_s16[tid] = 0;
    float c_r = 0.f;
    __syncthreads();

    int lane = tid & 63, w = tid >> 6;
    int kg = lane >> 3, cl = lane & 7;
    int col0 = w * 64 + cl * 8;
    int kp0 = kg * 16;
    int isTanh = (col0 >> 8) == 2;          // uniform per wave
    int nL = (kg < (KC_ / 16)) ? 16 : 0;    // LDS iters for this lane
    const float* xgb = Xg + (long)b * T_ * G4 + col0;
    const uint* ldsH = (const uint*)h_s16;

    for (int t = 0; t < T_; ++t) {
        // issue Xg loads early (independent of h)
        float4 xg0, xg1;
        if (kg == 0) {
            xg0 = *(const float4*)(xgb + (long)t * G4);
            xg1 = *(const float4*)(xgb + (long)t * G4 + 4);
        }
        float a[8] = {0.f, 0.f, 0.f, 0.f, 0.f, 0.f, 0.f, 0.f};
        #pragma unroll 4
        for (int i = 0; i < nL; ++i) {
            int kp = kp0 + i;
            half2f hv = __builtin_bit_cast(half2f, ldsH[kp]);
            const uint* wrow = (const uint*)(Wl + (size_t)kp * LDW_) + col0;
            uint4 u0 = *(const uint4*)wrow;
            uint4 u1 = *(const uint4*)(wrow + 4);
            a[0] = FDOT2(__builtin_bit_cast(half2f, u0.x), hv, a[0]);
            a[1] = FDOT2(__builtin_bit_cast(half2f, u0.y), hv, a[1]);
            a[2] = FDOT2(__builtin_bit_cast(half2f, u0.z), hv, a[2]);
            a[3] = FDOT2(__builtin_bit_cast(half2f, u0.w), hv, a[3]);
            a[4] = FDOT2(__builtin_bit_cast(half2f, u1.x), hv, a[4]);
            a[5] = FDOT2(__builtin_bit_cast(half2f, u1.y), hv, a[5]);
            a[6] = FDOT2(__builtin_bit_cast(half2f, u1.z), hv, a[6]);
            a[7] = FDOT2(__builtin_bit_cast(half2f, u1.w), hv, a[7]);
        }
        #pragma unroll 4
        for (int i = nL; i < 16; ++i) {
            int kp = kp0 + i;
            half2f hv = __builtin_bit_cast(half2f, ldsH[kp]);
            const uint* wrow = WPu + (long)kp * G4 + col0;
            uint4 u0 = *(const uint4*)wrow;
            uint4 u1 = *(const uint4*)(wrow + 4);
            a[0] = FDOT2(__builtin_bit_cast(half2f, u0.x), hv, a[0]);
            a[1] = FDOT2(__builtin_bit_cast(half2f, u0.y), hv, a[1]);
            a[2] = FDOT2(__builtin_bit_cast(half2f, u0.z), hv, a[2]);
            a[3] = FDOT2(__builtin_bit_cast(half2f, u0.w), hv, a[3]);
            a[4] = FDOT2(__builtin_bit_cast(half2f, u1.x), hv, a[4]);
            a[5] = FDOT2(__builtin_bit_cast(half2f, u1.y), hv, a[5]);
            a[6] = FDOT2(__builtin_bit_cast(half2f, u1.z), hv, a[6]);
            a[7] = FDOT2(__builtin_bit_cast(half2f, u1.w), hv, a[7]);
        }
        // butterfly reduce over kg (lanes stride 8)
        #pragma unroll
        for (int m = 8; m <= 32; m <<= 1) {
            #pragma unroll
            for (int j = 0; j < 8; ++j) a[j] += __shfl_xor(a[j], m);
        }
        if (kg == 0) {
            const float* xp0 = &xg0.x;
            const float* xp1 = &xg1.x;
            #pragma unroll
            for (int j = 0; j < 8; ++j) {
                float g = a[j] + (j < 4 ? xp0[j] : xp1[j - 4]);
                act_s[col0 + j] = isTanh ? tanhf(g) : sigf(g);
            }
        }
        __syncthreads();
        if (tid < H_) {
            float cn = act_s[H_ + tid] * c_r + act_s[tid] * act_s[2 * H_ + tid];
            c_r = cn;
            float h = act_s[3 * H_ + tid] * tanhf(cn);
            h_s16[tid] = f2h(h);
            if (t == T_ - 1) {
                hN[(long)b * H_ + tid] = h;
                cN[(long)b * H_ + tid] = c_r;
            }
        }
        __syncthreads();
    }
}

__global__ __launch_bounds__(256) void k_dec_cell(const float* __restrict__ G,
                                                  const float* __restrict__ cNb,
                                                  ushort* __restrict__ hdec) {
    long idx = (long)blockIdx.x * 256 + threadIdx.x;
    int m = (int)(idx >> 8);
    int j = (int)(idx & 255);
    int b = m / T_;
    const float* g = G + (long)m * G4 + j;
    float gi = g[0], gf = g[H_], gg = g[2 * H_], go = g[3 * H_];
    float cv = sigf(gf) * cNb[(long)b * H_ + j] + sigf(gi) * tanhf(gg);
    hdec[idx] = f2bf(sigf(go) * tanhf(cv));
}

__global__ __launch_bounds__(256) void k_mlp3(const float* __restrict__ z2,
                                              const float* __restrict__ W3,
                                              const float* __restrict__ b3,
                                              float* __restrict__ out) {
    int wave = threadIdx.x >> 6, lane = threadIdx.x & 63;
    int m = blockIdx.x * 4 + wave;
    const float* zr = z2 + (long)m * P2_;
    float s = zr[lane] * W3[lane] + zr[64 + lane] * W3[64 + lane];
    #pragma unroll
    for (int off = 32; off > 0; off >>= 1) s += __shfl_down(s, off);
    if (lane == 0) out[m] = sigf(s + b3[0]);
}

extern "C" void kernel_launch(void* const* d_in, const int* in_sizes, int n_in,
                              void* d_out, int out_size, void* d_ws, size_t ws_size,
                              hipStream_t stream)
{
    const int*   x    = (const int*)d_in[0];
    const float* emb  = (const float*)d_in[1];
    const float* W_ih = (const float*)d_in[2];
    const float* W_hh = (const float*)d_in[3];
    const float* b_ih = (const float*)d_in[4];
    const float* b_hh = (const float*)d_in[5];
    const float* W1   = (const float*)d_in[6];
    const float* b1   = (const float*)d_in[7];
    const float* W2   = (const float*)d_in[8];
    const float* b2   = (const float*)d_in[9];
    const float* W3   = (const float*)d_in[10];
    const float* b3   = (const float*)d_in[11];
    float* out = (float*)d_out;

    float* ws = (float*)d_ws;
    ushort* ebf  = (ushort*)ws;                 // B*S*E bf16 (3,276,800 f)
    float* Xg    = ws + 3276800;                // 26,214,400 f
    float* bsum  = Xg + 26214400;               // 1024
    float* hN    = bsum + 1024;                 // 65,536
    float* cN    = hN + 65536;                  // 65,536
    float* hhdec = cN + 65536;                  // 262,144
    uint*  WPu   = (uint*)(hhdec + 262144);     // 131,072 uints (512 KB)
    ushort* Wihb = (ushort*)(WPu + 131072);     // 131,072 ush
    ushort* W1T  = Wihb + 131072;               // 131,072 ush
    ushort* W2T  = W1T + 131072;                // 65,536 ush
    // reuse (stream-ordered):
    ushort* hdec_bf = ebf;
    ushort* z1b  = (ushort*)Xg;
    float*  z2   = Xg + 6553600;

    k_bsum<<<4, 256, 0, stream>>>(b_ih, b_hh, bsum);
    k_prep_wp<<<dim3(8, 32), 256, 0, stream>>>(W_hh, WPu);
    k_tr_bf16<<<dim3(16, 8),  256, 0, stream>>>(W1, W1T, H_, P1_);
    k_tr_bf16<<<dim3(4, 16),  256, 0, stream>>>(W2, W2T, P1_, P2_);
    k_cvt_bf16<<<512, 256, 0, stream>>>(W_ih, Wihb, G4 * E_);
    k_gather<<<B_ * S_, 128, 0, stream>>>(x, emb, ebf);

    // Xg = e_hist @ W_ih^T + bsum
    k_gemm_mfma<0, 0><<<dim3(G4 / 128, (B_ * T_) / 128), 256, 0, stream>>>(
        ebf, T_, (long)S_ * E_, (long)E_, Wihb, bsum, nullptr, 1,
        Xg, G4, E_);

    // persistent broadcast scan (fp16 W, LDS cache + dot2)
    size_t scan_smem = (size_t)KC_ * LDW_ * 2 + G4 * sizeof(float) + H_ * sizeof(ushort);
    k_lstm_scan<<<B_, 1024, scan_smem, stream>>>(Xg, WPu, hN, cN);

    // hhdec = hN @ W_hh^T + bsum (fp32, tiny)
    k_gemm<1, 0><<<dim3(G4 / 128, B_ / 64), 256, 0, stream>>>(
        hN, B_, 0L, (long)H_, W_hh, bsum, nullptr, 1,
        hhdec, B_, G4, H_);

    // Gdec = e_tgt @ W_ih^T + hhdec[b]
    k_gemm_mfma<0, 0><<<dim3(G4 / 128, (B_ * T_) / 128), 256, 0, stream>>>(
        ebf + T_ * E_, T_, (long)S_ * E_, (long)E_, Wihb, nullptr, hhdec, T_,
        Xg, G4, E_);

    // decode cell -> hdec_bf
    k_dec_cell<<<(B_ * T_ * H_) / 256, 256, 0, stream>>>(Xg, cN, hdec_bf);

    // z1 = relu(hdec @ W1 + b1) -> bf16
    k_gemm_mfma<1, 1><<<dim3(P1_ / 128, (B_ * T_) / 128), 256, 0, stream>>>(
        hdec_bf, B_ * T_, 0L, (long)H_, W1T, b1, nullptr, 1,
        z1b, P1_, H_);

    // z2 = relu(z1 @ W2 + b2) -> f32
    k_gemm_mfma<1, 0><<<dim3(P2_ / 128, (B_ * T_) / 128), 256, 0, stream>>>(
        z1b, B_ * T_, 0L, (long)P1_, W2T, b2, nullptr, 1,
        z2, P2_, P1_);

    // out = sigmoid(z2 . W3 + b3)
    k_mlp3<<<(B_ * T_) / 4, 256, 0, stream>>>(z2, W3, b3, out);
}

// Round 8
// 771.824 us; speedup vs baseline: 1.2201x; 1.2201x over previous
//
#include <hip/hip_runtime.h>
#include <hip/hip_bf16.h>
#include <math.h>

#define B_  256
#define S_  200
#define F_  10
#define T_  100
#define E_  128
#define H_  256
#define G4  1024   // 4*H
#define P1_ 512
#define P2_ 128

typedef __attribute__((ext_vector_type(8))) short short8;
typedef __attribute__((ext_vector_type(4))) float f32x4;
typedef _Float16 half2f __attribute__((ext_vector_type(2)));

#if __has_builtin(__builtin_amdgcn_fdot2)
#define FDOT2(w2, h2, acc) __builtin_amdgcn_fdot2((w2), (h2), (acc), false)
#else
#define FDOT2(w2, h2, acc) ((acc) + (float)((w2)[0]) * (float)((h2)[0]) + (float)((w2)[1]) * (float)((h2)[1]))
#endif
#define BCH2(u) __builtin_bit_cast(half2f, (u))

__device__ __forceinline__ float sigf(float x) { return 1.0f / (1.0f + expf(-x)); }
__device__ __forceinline__ ushort f2bf(float f) {
    __hip_bfloat16 v = __float2bfloat16(f);
    return *(ushort*)&v;
}
__device__ __forceinline__ ushort f2h(float f) {
    _Float16 h = (_Float16)f;
    return __builtin_bit_cast(ushort, h);
}

__global__ __launch_bounds__(256) void k_bsum(const float* __restrict__ bi,
                                              const float* __restrict__ bh,
                                              float* __restrict__ bs) {
    int i = blockIdx.x * 256 + threadIdx.x;
    if (i < G4) bs[i] = bi[i] + bh[i];
}

// W (R x C) f32 -> WT (C x R) bf16. grid (C/32, R/32), 256 thr.
__global__ __launch_bounds__(256) void k_tr_bf16(const float* __restrict__ W,
                                                 ushort* __restrict__ WT,
                                                 int R, int C) {
    __shared__ float t[32][33];
    int c0 = blockIdx.x * 32, r0 = blockIdx.y * 32;
    int lc = threadIdx.x & 31, lr = threadIdx.x >> 5;
    #pragma unroll
    for (int i = 0; i < 4; ++i)
        t[lr + 8 * i][lc] = W[(long)(r0 + lr + 8 * i) * C + c0 + lc];
    __syncthreads();
    #pragma unroll
    for (int i = 0; i < 4; ++i)
        WT[(long)(c0 + lr + 8 * i) * R + r0 + lc] = f2bf(t[lc][lr + 8 * i]);
}

// W_hh (1024 x 256) f32 -> WPu: k-pair-interleaved fp16.
// WPu[kp*1024 + c] = pack(f16(W[c][2kp]), f16(W[c][2kp+1])), kp=0..127.
__global__ __launch_bounds__(256) void k_prep_wp(const float* __restrict__ W,
                                                 uint* __restrict__ WPu) {
    __shared__ float t[32][33];
    int k0 = blockIdx.x * 32, c0 = blockIdx.y * 32;
    int lk = threadIdx.x & 31, lc8 = threadIdx.x >> 5;
    #pragma unroll
    for (int i = 0; i < 4; ++i)
        t[lc8 + 8 * i][lk] = W[(long)(c0 + lc8 + 8 * i) * 256 + k0 + lk];
    __syncthreads();
    int kpl = threadIdx.x >> 4;   // 0..15
    int ccl = threadIdx.x & 15;   // 0..15
    #pragma unroll
    for (int hf = 0; hf < 2; ++hf) {
        int c = ccl + 16 * hf;
        uint lo = f2h(t[c][2 * kpl]);
        uint hi = f2h(t[c][2 * kpl + 1]);
        WPu[(long)(k0 / 2 + kpl) * G4 + c0 + c] = lo | (hi << 16);
    }
}

__global__ __launch_bounds__(256) void k_cvt_bf16(const float* __restrict__ W,
                                                  ushort* __restrict__ O, int n) {
    int i = blockIdx.x * 256 + threadIdx.x;
    if (i < n) O[i] = f2bf(W[i]);
}

// one block per (b,s); 128 threads = one e-dim each; bf16 out
__global__ __launch_bounds__(128) void k_gather(const int* __restrict__ x,
                                                const float* __restrict__ emb,
                                                ushort* __restrict__ e) {
    int bs = blockIdx.x;
    int t  = threadIdx.x;
    const int* xr = x + (long)bs * F_;
    float acc = 0.f;
    #pragma unroll
    for (int f = 0; f < F_; ++f) acc += emb[(long)xr[f] * E_ + t];
    e[(long)bs * E_ + t] = f2bf(acc * (1.0f / F_));
}

// ---------------- bf16 MFMA GEMM (unchanged) ----------------
template<int ACT, int OUTBF>
__global__ __launch_bounds__(256) void k_gemm_mfma(
    const ushort* __restrict__ A, int rowDiv, long sOuter, long sInner,
    const ushort* __restrict__ Bm,
    const float* __restrict__ bias,
    const float* __restrict__ rowAdd, int rowAddDiv,
    void* __restrict__ Cout, int N, int K)
{
    constexpr int LDT = 40;
    __shared__ ushort Al[128 * LDT];
    __shared__ ushort Bl[128 * LDT];
    int tid = threadIdx.x;
    int n0 = blockIdx.x * 128;
    int m0 = blockIdx.y * 128;

    int rA = tid >> 2, qA = tid & 3;
    int m_lo = m0 + rA, m_hi = m_lo + 64;
    long a0 = (long)(m_lo / rowDiv) * sOuter + (long)(m_lo % rowDiv) * sInner + qA * 8;
    long a1 = (long)(m_hi / rowDiv) * sOuter + (long)(m_hi % rowDiv) * sInner + qA * 8;
    const ushort* b0p = Bm + (long)(n0 + rA) * K + qA * 8;
    const ushort* b1p = Bm + (long)(n0 + rA + 64) * K + qA * 8;

    int lane = tid & 63, wave = tid >> 6;
    int wr = wave >> 1, wc = wave & 1;
    int lrow = lane & 15, lkh = lane >> 4;

    const f32x4 fz = {0.f, 0.f, 0.f, 0.f};
    f32x4 acc[4][4];
    #pragma unroll
    for (int i = 0; i < 4; ++i)
        #pragma unroll
        for (int j = 0; j < 4; ++j) acc[i][j] = fz;

    int nk = K >> 5;
    for (int kc = 0; kc < nk; ++kc) {
        uint4 va0 = *(const uint4*)(A + a0 + kc * 32);
        uint4 va1 = *(const uint4*)(A + a1 + kc * 32);
        uint4 vb0 = *(const uint4*)(b0p + kc * 32);
        uint4 vb1 = *(const uint4*)(b1p + kc * 32);
        *(uint4*)&Al[rA * LDT + qA * 8]        = va0;
        *(uint4*)&Al[(rA + 64) * LDT + qA * 8] = va1;
        *(uint4*)&Bl[rA * LDT + qA * 8]        = vb0;
        *(uint4*)&Bl[(rA + 64) * LDT + qA * 8] = vb1;
        __syncthreads();
        short8 af[4], bfr[4];
        #pragma unroll
        for (int mi = 0; mi < 4; ++mi)
            af[mi] = *(const short8*)&Al[(wr * 64 + mi * 16 + lrow) * LDT + lkh * 8];
        #pragma unroll
        for (int ni = 0; ni < 4; ++ni)
            bfr[ni] = *(const short8*)&Bl[(wc * 64 + ni * 16 + lrow) * LDT + lkh * 8];
        #pragma unroll
        for (int mi = 0; mi < 4; ++mi)
            #pragma unroll
            for (int ni = 0; ni < 4; ++ni)
                acc[mi][ni] = __builtin_amdgcn_mfma_f32_16x16x32_bf16(
                    af[mi], bfr[ni], acc[mi][ni], 0, 0, 0);
        __syncthreads();
    }
    #pragma unroll
    for (int mi = 0; mi < 4; ++mi) {
        #pragma unroll
        for (int r = 0; r < 4; ++r) {
            int m = m0 + wr * 64 + mi * 16 + lkh * 4 + r;
            long rowoff = rowAdd ? (long)(m / rowAddDiv) * N : 0;
            #pragma unroll
            for (int ni = 0; ni < 4; ++ni) {
                int n = n0 + wc * 64 + ni * 16 + lrow;
                float v = acc[mi][ni][r];
                if (bias)   v += bias[n];
                if (rowAdd) v += rowAdd[rowoff + n];
                if (ACT)    v = fmaxf(v, 0.f);
                if (OUTBF) ((ushort*)Cout)[(long)m * N + n] = f2bf(v);
                else       ((float*)Cout)[(long)m * N + n] = v;
            }
        }
    }
}

// ---------------- fp32 GEMM (kept for small hhdec) ----------------
template<int BT, int ACT>
__global__ __launch_bounds__(256) void k_gemm(
    const float* __restrict__ A, int rowDiv, long sOuter, long sInner,
    const float* __restrict__ Bm,
    const float* __restrict__ bias,
    const float* __restrict__ rowAdd, int rowAddDiv,
    float* __restrict__ C, int M, int N, int K)
{
    __shared__ float Al[32 * 66];
    __shared__ float Bl[32 * 130];
    int tid = threadIdx.x;
    int n0 = blockIdx.x * 128;
    int m0 = blockIdx.y * 64;
    int cA = tid & 31;
    int rA = tid >> 5;
    long rb[8];
    #pragma unroll
    for (int i = 0; i < 8; ++i) {
        int m = m0 + rA + 8 * i;
        rb[i] = (long)(m / rowDiv) * sOuter + (long)(m % rowDiv) * sInner;
    }
    int tr = tid >> 5, tc = tid & 31;
    float acc[8][4] = {};
    int nk = K >> 5;
    for (int kc = 0; kc < nk; ++kc) {
        #pragma unroll
        for (int i = 0; i < 8; ++i)
            Al[cA * 66 + rA + 8 * i] = A[rb[i] + kc * 32 + cA];
        if (BT) {
            #pragma unroll
            for (int i = 0; i < 16; ++i) {
                int lin = tid + 256 * i;
                int n = lin >> 5, k = lin & 31;
                Bl[k * 130 + n] = Bm[(long)(n0 + n) * K + kc * 32 + k];
            }
        } else {
            #pragma unroll
            for (int i = 0; i < 16; ++i) {
                int lin = tid + 256 * i;
                int k = lin >> 7, n = lin & 127;
                Bl[k * 130 + n] = Bm[(long)(kc * 32 + k) * N + n0 + n];
            }
        }
        __syncthreads();
        #pragma unroll 4
        for (int k = 0; k < 32; ++k) {
            float a_[8], b_[4];
            *(float2*)&a_[0] = *(float2*)&Al[k * 66 + tr * 8];
            *(float2*)&a_[2] = *(float2*)&Al[k * 66 + tr * 8 + 2];
            *(float2*)&a_[4] = *(float2*)&Al[k * 66 + tr * 8 + 4];
            *(float2*)&a_[6] = *(float2*)&Al[k * 66 + tr * 8 + 6];
            *(float2*)&b_[0] = *(float2*)&Bl[k * 130 + tc * 4];
            *(float2*)&b_[2] = *(float2*)&Bl[k * 130 + tc * 4 + 2];
            #pragma unroll
            for (int i = 0; i < 8; ++i)
                #pragma unroll
                for (int j = 0; j < 4; ++j)
                    acc[i][j] += a_[i] * b_[j];
        }
        __syncthreads();
    }
    #pragma unroll
    for (int i = 0; i < 8; ++i) {
        int m = m0 + tr * 8 + i;
        int n = n0 + tc * 4;
        float4 v;
        float* vp = &v.x;
        #pragma unroll
        for (int j = 0; j < 4; ++j) {
            float t = acc[i][j];
            if (bias)   t += bias[n + j];
            if (rowAdd) t += rowAdd[(long)(m / rowAddDiv) * N + n + j];
            if (ACT == 1) t = fmaxf(t, 0.f);
            vp[j] = t;
        }
        *(float4*)&C[(long)m * N + n] = v;
    }
}

// Persistent batch-parallel LSTM scan: broadcast W stream + wave-uniform LDS
// W-cache + dot2. One block per batch row, 1024 threads.
// kg = tid>>8 (4 k-groups x 4 whole waves -> per-wave-uniform LDS/global split);
// thread owns 4 gate-cols c0..c0+3 and 32 kpairs. kpair rows 0..KC2-1 cached
// in LDS (loaded once); rest streamed from L2. Partials via red[4][1024].
#define KC2 33
__global__ __launch_bounds__(1024) void k_lstm_scan(
    const float* __restrict__ Xg, const uint* __restrict__ WPu,
    float* __restrict__ hN, float* __restrict__ cN)
{
    extern __shared__ __align__(16) char smem[];
    uint*   WlU   = (uint*)smem;                         // KC2*1024 uints (132 KB)
    float*  red   = (float*)(smem + KC2 * 4096);         // 4*1024 f (16 KB)
    float*  act_s = red + 4 * G4 / 4 * 4;                // 1024 f (4 KB)
    ushort* h16   = (ushort*)(act_s + G4);               // 256 ush
    const uint* h16u = (const uint*)(act_s + G4);
    int tid = threadIdx.x;
    int b   = blockIdx.x;
    int kg  = tid >> 8;            // 0..3, uniform per wave
    int c0  = (tid & 255) * 4;     // col base (uint units)

    // one-time W cache load (kpair rows 0..KC2-1), coalesced
    for (int i = tid; i < KC2 * 1024; i += 1024)
        WlU[i] = WPu[(long)(i >> 10) * G4 + (i & 1023)];
    if (tid < H_) h16[tid] = 0;
    float c_r = 0.f;
    __syncthreads();

    int kpLo = kg * 32;
    int nLds = KC2 - kpLo;
    nLds = nLds < 0 ? 0 : (nLds > 32 ? 32 : nLds);       // uniform per wave
    const float* xgb = Xg + (long)b * T_ * G4;

    for (int t = 0; t < T_; ++t) {
        float xv = xgb[(long)t * G4 + tid];   // independent prefetch
        float a0 = 0.f, a1 = 0.f, a2 = 0.f, a3 = 0.f;
        #pragma unroll 8
        for (int i = 0; i < nLds; ++i) {
            int kp = kpLo + i;
            half2f hv = BCH2(h16u[kp]);
            uint4 u = *(const uint4*)(WlU + (size_t)kp * 1024 + c0);
            a0 = FDOT2(BCH2(u.x), hv, a0);
            a1 = FDOT2(BCH2(u.y), hv, a1);
            a2 = FDOT2(BCH2(u.z), hv, a2);
            a3 = FDOT2(BCH2(u.w), hv, a3);
        }
        #pragma unroll 8
        for (int i = nLds; i < 32; ++i) {
            int kp = kpLo + i;
            half2f hv = BCH2(h16u[kp]);
            uint4 u = *(const uint4*)(WPu + (long)kp * G4 + c0);
            a0 = FDOT2(BCH2(u.x), hv, a0);
            a1 = FDOT2(BCH2(u.y), hv, a1);
            a2 = FDOT2(BCH2(u.z), hv, a2);
            a3 = FDOT2(BCH2(u.w), hv, a3);
        }
        *(float4*)&red[kg * G4 + c0] = make_float4(a0, a1, a2, a3);
        __syncthreads();
        float g = red[tid] + red[G4 + tid] + red[2 * G4 + tid] + red[3 * G4 + tid] + xv;
        act_s[tid] = ((tid >> 8) == 2) ? tanhf(g) : sigf(g);
        __syncthreads();
        if (tid < H_) {
            float cn = act_s[H_ + tid] * c_r + act_s[tid] * act_s[2 * H_ + tid];
            c_r = cn;
            float h = act_s[3 * H_ + tid] * tanhf(cn);
            h16[tid] = f2h(h);
            if (t == T_ - 1) {
                hN[(long)b * H_ + tid] = h;
                cN[(long)b * H_ + tid] = c_r;
            }
        }
        __syncthreads();
    }
}

__global__ __launch_bounds__(256) void k_dec_cell(const float* __restrict__ G,
                                                  const float* __restrict__ cNb,
                                                  ushort* __restrict__ hdec) {
    long idx = (long)blockIdx.x * 256 + threadIdx.x;
    int m = (int)(idx >> 8);
    int j = (int)(idx & 255);
    int b = m / T_;
    const float* g = G + (long)m * G4 + j;
    float gi = g[0], gf = g[H_], gg = g[2 * H_], go = g[3 * H_];
    float cv = sigf(gf) * cNb[(long)b * H_ + j] + sigf(gi) * tanhf(gg);
    hdec[idx] = f2bf(sigf(go) * tanhf(cv));
}

__global__ __launch_bounds__(256) void k_mlp3(const float* __restrict__ z2,
                                              const float* __restrict__ W3,
                                              const float* __restrict__ b3,
                                              float* __restrict__ out) {
    int wave = threadIdx.x >> 6, lane = threadIdx.x & 63;
    int m = blockIdx.x * 4 + wave;
    const float* zr = z2 + (long)m * P2_;
    float s = zr[lane] * W3[lane] + zr[64 + lane] * W3[64 + lane];
    #pragma unroll
    for (int off = 32; off > 0; off >>= 1) s += __shfl_down(s, off);
    if (lane == 0) out[m] = sigf(s + b3[0]);
}

extern "C" void kernel_launch(void* const* d_in, const int* in_sizes, int n_in,
                              void* d_out, int out_size, void* d_ws, size_t ws_size,
                              hipStream_t stream)
{
    const int*   x    = (const int*)d_in[0];
    const float* emb  = (const float*)d_in[1];
    const float* W_ih = (const float*)d_in[2];
    const float* W_hh = (const float*)d_in[3];
    const float* b_ih = (const float*)d_in[4];
    const float* b_hh = (const float*)d_in[5];
    const float* W1   = (const float*)d_in[6];
    const float* b1   = (const float*)d_in[7];
    const float* W2   = (const float*)d_in[8];
    const float* b2   = (const float*)d_in[9];
    const float* W3   = (const float*)d_in[10];
    const float* b3   = (const float*)d_in[11];
    float* out = (float*)d_out;

    float* ws = (float*)d_ws;
    ushort* ebf  = (ushort*)ws;                 // B*S*E bf16 (3,276,800 f)
    float* Xg    = ws + 3276800;                // 26,214,400 f
    float* bsum  = Xg + 26214400;               // 1024
    float* hN    = bsum + 1024;                 // 65,536
    float* cN    = hN + 65536;                  // 65,536
    float* hhdec = cN + 65536;                  // 262,144
    uint*  WPu   = (uint*)(hhdec + 262144);     // 131,072 uints (512 KB)
    ushort* Wihb = (ushort*)(WPu + 131072);     // 131,072 ush
    ushort* W1T  = Wihb + 131072;               // 131,072 ush
    ushort* W2T  = W1T + 131072;                // 65,536 ush
    // reuse (stream-ordered):
    ushort* hdec_bf = ebf;
    ushort* z1b  = (ushort*)Xg;
    float*  z2   = Xg + 6553600;

    k_bsum<<<4, 256, 0, stream>>>(b_ih, b_hh, bsum);
    k_prep_wp<<<dim3(8, 32), 256, 0, stream>>>(W_hh, WPu);
    k_tr_bf16<<<dim3(16, 8),  256, 0, stream>>>(W1, W1T, H_, P1_);
    k_tr_bf16<<<dim3(4, 16),  256, 0, stream>>>(W2, W2T, P1_, P2_);
    k_cvt_bf16<<<512, 256, 0, stream>>>(W_ih, Wihb, G4 * E_);
    k_gather<<<B_ * S_, 128, 0, stream>>>(x, emb, ebf);

    // Xg = e_hist @ W_ih^T + bsum
    k_gemm_mfma<0, 0><<<dim3(G4 / 128, (B_ * T_) / 128), 256, 0, stream>>>(
        ebf, T_, (long)S_ * E_, (long)E_, Wihb, bsum, nullptr, 1,
        Xg, G4, E_);

    // persistent broadcast scan (fp16 W, wave-uniform LDS cache + dot2)
    size_t scan_smem = (size_t)KC2 * 4096 + 4 * G4 * sizeof(float)
                     + G4 * sizeof(float) + H_ * sizeof(ushort);
    k_lstm_scan<<<B_, 1024, scan_smem, stream>>>(Xg, WPu, hN, cN);

    // hhdec = hN @ W_hh^T + bsum (fp32, tiny)
    k_gemm<1, 0><<<dim3(G4 / 128, B_ / 64), 256, 0, stream>>>(
        hN, B_, 0L, (long)H_, W_hh, bsum, nullptr, 1,
        hhdec, B_, G4, H_);

    // Gdec = e_tgt @ W_ih^T + hhdec[b]
    k_gemm_mfma<0, 0><<<dim3(G4 / 128, (B_ * T_) / 128), 256, 0, stream>>>(
        ebf + T_ * E_, T_, (long)S_ * E_, (long)E_, Wihb, nullptr, hhdec, T_,
        Xg, G4, E_);

    // decode cell -> hdec_bf
    k_dec_cell<<<(B_ * T_ * H_) / 256, 256, 0, stream>>>(Xg, cN, hdec_bf);

    // z1 = relu(hdec @ W1 + b1) -> bf16
    k_gemm_mfma<1, 1><<<dim3(P1_ / 128, (B_ * T_) / 128), 256, 0, stream>>>(
        hdec_bf, B_ * T_, 0L, (long)H_, W1T, b1, nullptr, 1,
        z1b, P1_, H_);

    // z2 = relu(z1 @ W2 + b2) -> f32
    k_gemm_mfma<1, 0><<<dim3(P2_ / 128, (B_ * T_) / 128), 256, 0, stream>>>(
        z1b, B_ * T_, 0L, (long)P1_, W2T, b2, nullptr, 1,
        z2, P2_, P1_);

    // out = sigmoid(z2 . W3 + b3)
    k_mlp3<<<(B_ * T_) / 4, 256, 0, stream>>>(z2, W3, b3, out);
}

// Round 9
// 584.162 us; speedup vs baseline: 1.6120x; 1.3212x over previous
//
#include <hip/hip_runtime.h>
#include <hip/hip_bf16.h>
#include <math.h>

#define B_  256
#define S_  200
#define F_  10
#define T_  100
#define E_  128
#define H_  256
#define G4  1024   // 4*H
#define P1_ 512
#define P2_ 128

typedef __attribute__((ext_vector_type(8))) short short8;
typedef __attribute__((ext_vector_type(4))) float f32x4;
typedef _Float16 half2f __attribute__((ext_vector_type(2)));

#if __has_builtin(__builtin_amdgcn_fdot2)
#define FDOT2(w2, h2, acc) __builtin_amdgcn_fdot2((w2), (h2), (acc), false)
#else
#define FDOT2(w2, h2, acc) ((acc) + (float)((w2)[0]) * (float)((h2)[0]) + (float)((w2)[1]) * (float)((h2)[1]))
#endif
#define BCH2(u) __builtin_bit_cast(half2f, (u))
#define DO4(W0, W1, W2, W3, HH) \
    a = FDOT2(BCH2(W0), BCH2((HH).x), a); \
    a = FDOT2(BCH2(W1), BCH2((HH).y), a); \
    a = FDOT2(BCH2(W2), BCH2((HH).z), a); \
    a = FDOT2(BCH2(W3), BCH2((HH).w), a);

// scan W placement (kpair rows of 1024 uints): LDS | VGPR | streamed
#define NL_ 36
#define NR_ 80
#define NS_ 12

__device__ __forceinline__ float sigf(float x) { return 1.0f / (1.0f + expf(-x)); }
__device__ __forceinline__ ushort f2bf(float f) {
    __hip_bfloat16 v = __float2bfloat16(f);
    return *(ushort*)&v;
}
__device__ __forceinline__ ushort f2h(float f) {
    _Float16 h = (_Float16)f;
    return __builtin_bit_cast(ushort, h);
}

__global__ __launch_bounds__(256) void k_bsum(const float* __restrict__ bi,
                                              const float* __restrict__ bh,
                                              float* __restrict__ bs) {
    int i = blockIdx.x * 256 + threadIdx.x;
    if (i < G4) bs[i] = bi[i] + bh[i];
}

// W (R x C) f32 -> WT (C x R) bf16. grid (C/32, R/32), 256 thr.
__global__ __launch_bounds__(256) void k_tr_bf16(const float* __restrict__ W,
                                                 ushort* __restrict__ WT,
                                                 int R, int C) {
    __shared__ float t[32][33];
    int c0 = blockIdx.x * 32, r0 = blockIdx.y * 32;
    int lc = threadIdx.x & 31, lr = threadIdx.x >> 5;
    #pragma unroll
    for (int i = 0; i < 4; ++i)
        t[lr + 8 * i][lc] = W[(long)(r0 + lr + 8 * i) * C + c0 + lc];
    __syncthreads();
    #pragma unroll
    for (int i = 0; i < 4; ++i)
        WT[(long)(c0 + lr + 8 * i) * R + r0 + lc] = f2bf(t[lc][lr + 8 * i]);
}

// W_hh (1024 x 256) f32 -> WPu: k-pair-interleaved fp16.
// WPu[kp*1024 + c] = pack(f16(W[c][2kp]), f16(W[c][2kp+1])), kp=0..127.
__global__ __launch_bounds__(256) void k_prep_wp(const float* __restrict__ W,
                                                 uint* __restrict__ WPu) {
    __shared__ float t[32][33];
    int k0 = blockIdx.x * 32, c0 = blockIdx.y * 32;
    int lk = threadIdx.x & 31, lc8 = threadIdx.x >> 5;
    #pragma unroll
    for (int i = 0; i < 4; ++i)
        t[lc8 + 8 * i][lk] = W[(long)(c0 + lc8 + 8 * i) * 256 + k0 + lk];
    __syncthreads();
    int kpl = threadIdx.x >> 4;   // 0..15
    int ccl = threadIdx.x & 15;   // 0..15
    #pragma unroll
    for (int hf = 0; hf < 2; ++hf) {
        int c = ccl + 16 * hf;
        uint lo = f2h(t[c][2 * kpl]);
        uint hi = f2h(t[c][2 * kpl + 1]);
        WPu[(long)(k0 / 2 + kpl) * G4 + c0 + c] = lo | (hi << 16);
    }
}

__global__ __launch_bounds__(256) void k_cvt_bf16(const float* __restrict__ W,
                                                  ushort* __restrict__ O, int n) {
    int i = blockIdx.x * 256 + threadIdx.x;
    if (i < n) O[i] = f2bf(W[i]);
}

// one block per (b,s); 128 threads = one e-dim each; bf16 out
__global__ __launch_bounds__(128) void k_gather(const int* __restrict__ x,
                                                const float* __restrict__ emb,
                                                ushort* __restrict__ e) {
    int bs = blockIdx.x;
    int t  = threadIdx.x;
    const int* xr = x + (long)bs * F_;
    float acc = 0.f;
    #pragma unroll
    for (int f = 0; f < F_; ++f) acc += emb[(long)xr[f] * E_ + t];
    e[(long)bs * E_ + t] = f2bf(acc * (1.0f / F_));
}

// ---------------- bf16 MFMA GEMM (unchanged) ----------------
template<int ACT, int OUTBF>
__global__ __launch_bounds__(256) void k_gemm_mfma(
    const ushort* __restrict__ A, int rowDiv, long sOuter, long sInner,
    const ushort* __restrict__ Bm,
    const float* __restrict__ bias,
    const float* __restrict__ rowAdd, int rowAddDiv,
    void* __restrict__ Cout, int N, int K)
{
    constexpr int LDT = 40;
    __shared__ ushort Al[128 * LDT];
    __shared__ ushort Bl[128 * LDT];
    int tid = threadIdx.x;
    int n0 = blockIdx.x * 128;
    int m0 = blockIdx.y * 128;

    int rA = tid >> 2, qA = tid & 3;
    int m_lo = m0 + rA, m_hi = m_lo + 64;
    long a0 = (long)(m_lo / rowDiv) * sOuter + (long)(m_lo % rowDiv) * sInner + qA * 8;
    long a1 = (long)(m_hi / rowDiv) * sOuter + (long)(m_hi % rowDiv) * sInner + qA * 8;
    const ushort* b0p = Bm + (long)(n0 + rA) * K + qA * 8;
    const ushort* b1p = Bm + (long)(n0 + rA + 64) * K + qA * 8;

    int lane = tid & 63, wave = tid >> 6;
    int wr = wave >> 1, wc = wave & 1;
    int lrow = lane & 15, lkh = lane >> 4;

    const f32x4 fz = {0.f, 0.f, 0.f, 0.f};
    f32x4 acc[4][4];
    #pragma unroll
    for (int i = 0; i < 4; ++i)
        #pragma unroll
        for (int j = 0; j < 4; ++j) acc[i][j] = fz;

    int nk = K >> 5;
    for (int kc = 0; kc < nk; ++kc) {
        uint4 va0 = *(const uint4*)(A + a0 + kc * 32);
        uint4 va1 = *(const uint4*)(A + a1 + kc * 32);
        uint4 vb0 = *(const uint4*)(b0p + kc * 32);
        uint4 vb1 = *(const uint4*)(b1p + kc * 32);
        *(uint4*)&Al[rA * LDT + qA * 8]        = va0;
        *(uint4*)&Al[(rA + 64) * LDT + qA * 8] = va1;
        *(uint4*)&Bl[rA * LDT + qA * 8]        = vb0;
        *(uint4*)&Bl[(rA + 64) * LDT + qA * 8] = vb1;
        __syncthreads();
        short8 af[4], bfr[4];
        #pragma unroll
        for (int mi = 0; mi < 4; ++mi)
            af[mi] = *(const short8*)&Al[(wr * 64 + mi * 16 + lrow) * LDT + lkh * 8];
        #pragma unroll
        for (int ni = 0; ni < 4; ++ni)
            bfr[ni] = *(const short8*)&Bl[(wc * 64 + ni * 16 + lrow) * LDT + lkh * 8];
        #pragma unroll
        for (int mi = 0; mi < 4; ++mi)
            #pragma unroll
            for (int ni = 0; ni < 4; ++ni)
                acc[mi][ni] = __builtin_amdgcn_mfma_f32_16x16x32_bf16(
                    af[mi], bfr[ni], acc[mi][ni], 0, 0, 0);
        __syncthreads();
    }
    #pragma unroll
    for (int mi = 0; mi < 4; ++mi) {
        #pragma unroll
        for (int r = 0; r < 4; ++r) {
            int m = m0 + wr * 64 + mi * 16 + lkh * 4 + r;
            long rowoff = rowAdd ? (long)(m / rowAddDiv) * N : 0;
            #pragma unroll
            for (int ni = 0; ni < 4; ++ni) {
                int n = n0 + wc * 64 + ni * 16 + lrow;
                float v = acc[mi][ni][r];
                if (bias)   v += bias[n];
                if (rowAdd) v += rowAdd[rowoff + n];
                if (ACT)    v = fmaxf(v, 0.f);
                if (OUTBF) ((ushort*)Cout)[(long)m * N + n] = f2bf(v);
                else       ((float*)Cout)[(long)m * N + n] = v;
            }
        }
    }
}

// ---------------- fp32 GEMM (kept for small hhdec) ----------------
template<int BT, int ACT>
__global__ __launch_bounds__(256) void k_gemm(
    const float* __restrict__ A, int rowDiv, long sOuter, long sInner,
    const float* __restrict__ Bm,
    const float* __restrict__ bias,
    const float* __restrict__ rowAdd, int rowAddDiv,
    float* __restrict__ C, int M, int N, int K)
{
    __shared__ float Al[32 * 66];
    __shared__ float Bl[32 * 130];
    int tid = threadIdx.x;
    int n0 = blockIdx.x * 128;
    int m0 = blockIdx.y * 64;
    int cA = tid & 31;
    int rA = tid >> 5;
    long rb[8];
    #pragma unroll
    for (int i = 0; i < 8; ++i) {
        int m = m0 + rA + 8 * i;
        rb[i] = (long)(m / rowDiv) * sOuter + (long)(m % rowDiv) * sInner;
    }
    int tr = tid >> 5, tc = tid & 31;
    float acc[8][4] = {};
    int nk = K >> 5;
    for (int kc = 0; kc < nk; ++kc) {
        #pragma unroll
        for (int i = 0; i < 8; ++i)
            Al[cA * 66 + rA + 8 * i] = A[rb[i] + kc * 32 + cA];
        if (BT) {
            #pragma unroll
            for (int i = 0; i < 16; ++i) {
                int lin = tid + 256 * i;
                int n = lin >> 5, k = lin & 31;
                Bl[k * 130 + n] = Bm[(long)(n0 + n) * K + kc * 32 + k];
            }
        } else {
            #pragma unroll
            for (int i = 0; i < 16; ++i) {
                int lin = tid + 256 * i;
                int k = lin >> 7, n = lin & 127;
                Bl[k * 130 + n] = Bm[(long)(kc * 32 + k) * N + n0 + n];
            }
        }
        __syncthreads();
        #pragma unroll 4
        for (int k = 0; k < 32; ++k) {
            float a_[8], b_[4];
            *(float2*)&a_[0] = *(float2*)&Al[k * 66 + tr * 8];
            *(float2*)&a_[2] = *(float2*)&Al[k * 66 + tr * 8 + 2];
            *(float2*)&a_[4] = *(float2*)&Al[k * 66 + tr * 8 + 4];
            *(float2*)&a_[6] = *(float2*)&Al[k * 66 + tr * 8 + 6];
            *(float2*)&b_[0] = *(float2*)&Bl[k * 130 + tc * 4];
            *(float2*)&b_[2] = *(float2*)&Bl[k * 130 + tc * 4 + 2];
            #pragma unroll
            for (int i = 0; i < 8; ++i)
                #pragma unroll
                for (int j = 0; j < 4; ++j)
                    acc[i][j] += a_[i] * b_[j];
        }
        __syncthreads();
    }
    #pragma unroll
    for (int i = 0; i < 8; ++i) {
        int m = m0 + tr * 8 + i;
        int n = n0 + tc * 4;
        float4 v;
        float* vp = &v.x;
        #pragma unroll
        for (int j = 0; j < 4; ++j) {
            float t = acc[i][j];
            if (bias)   t += bias[n + j];
            if (rowAdd) t += rowAdd[(long)(m / rowAddDiv) * N + n + j];
            if (ACT == 1) t = fmaxf(t, 0.f);
            vp[j] = t;
        }
        *(float4*)&C[(long)m * N + n] = v;
    }
}

// Persistent LSTM scan, W fully resident: one gate-column per thread.
// 1024 threads/block, one block per batch row. W kpair rows (packed fp16):
//   kp 0..NL_-1      in LDS (loaded once)
//   kp NL_..NL_+NR_-1 in VGPRs (wr[], static indexing)
//   kp NL_+NR_..127  streamed from L2 (loads issued at step top)
// No cross-thread reduction: each thread's gate is a full 256-dot (1 f32 acc).
__global__ __launch_bounds__(1024) void k_lstm_scan(
    const float* __restrict__ Xg, const uint* __restrict__ WPu,
    float* __restrict__ hN, float* __restrict__ cN)
{
    extern __shared__ __align__(16) char smem[];
    uint*   Wl    = (uint*)smem;                    // NL_*1024 uints (144 KB)
    float*  act_s = (float*)(smem + NL_ * 4096);    // 1024 f32 (4 KB)
    uint*   h16u  = (uint*)(act_s + G4);            // 128 uints (packed f16 h)
    ushort* h16   = (ushort*)h16u;
    int tid = threadIdx.x;
    int b   = blockIdx.x;

    // one-time LDS W fill (coalesced)
    for (int i = tid; i < NL_ * 1024; i += 1024)
        Wl[i] = WPu[(long)(i >> 10) * G4 + (i & 1023)];
    // one-time VGPR W fill (row-coalesced dword loads)
    uint wr[NR_];
    #pragma unroll
    for (int i = 0; i < NR_; ++i)
        wr[i] = WPu[(long)(NL_ + i) * G4 + tid];
    if (tid < 128) h16u[tid] = 0;
    float c_r = 0.f;
    __syncthreads();

    int isTanh = (tid >> 8) == 2;                   // uniform per wave
    const float* xgp = Xg + (long)b * T_ * G4 + tid;

    for (int t = 0; t < T_; ++t) {
        float xv = xgp[(long)t * G4];               // independent prefetch
        uint ws[NS_];
        #pragma unroll
        for (int i = 0; i < NS_; ++i)               // streamed rows: issue early
            ws[i] = WPu[(long)(NL_ + NR_ + i) * G4 + tid];
        float a = 0.f;
        #pragma unroll
        for (int c4 = 0; c4 < NL_ / 4; ++c4) {      // LDS rows
            uint4 hh = *(const uint4*)(h16u + 4 * c4);
            uint w0 = Wl[(4 * c4 + 0) * 1024 + tid];
            uint w1 = Wl[(4 * c4 + 1) * 1024 + tid];
            uint w2 = Wl[(4 * c4 + 2) * 1024 + tid];
            uint w3 = Wl[(4 * c4 + 3) * 1024 + tid];
            DO4(w0, w1, w2, w3, hh);
        }
        #pragma unroll
        for (int c4 = 0; c4 < NR_ / 4; ++c4) {      // VGPR rows
            uint4 hh = *(const uint4*)(h16u + NL_ + 4 * c4);
            DO4(wr[4 * c4], wr[4 * c4 + 1], wr[4 * c4 + 2], wr[4 * c4 + 3], hh);
        }
        #pragma unroll
        for (int c4 = 0; c4 < NS_ / 4; ++c4) {      // streamed rows (loads done)
            uint4 hh = *(const uint4*)(h16u + NL_ + NR_ + 4 * c4);
            DO4(ws[4 * c4], ws[4 * c4 + 1], ws[4 * c4 + 2], ws[4 * c4 + 3], hh);
        }
        float g = a + xv;
        act_s[tid] = isTanh ? tanhf(g) : sigf(g);
        __syncthreads();
        if (tid < H_) {
            float cn = act_s[H_ + tid] * c_r + act_s[tid] * act_s[2 * H_ + tid];
            c_r = cn;
            float h = act_s[3 * H_ + tid] * tanhf(cn);
            h16[tid] = f2h(h);
            if (t == T_ - 1) {
                hN[(long)b * H_ + tid] = h;
                cN[(long)b * H_ + tid] = c_r;
            }
        }
        __syncthreads();
    }
}

__global__ __launch_bounds__(256) void k_dec_cell(const float* __restrict__ G,
                                                  const float* __restrict__ cNb,
                                                  ushort* __restrict__ hdec) {
    long idx = (long)blockIdx.x * 256 + threadIdx.x;
    int m = (int)(idx >> 8);
    int j = (int)(idx & 255);
    int b = m / T_;
    const float* g = G + (long)m * G4 + j;
    float gi = g[0], gf = g[H_], gg = g[2 * H_], go = g[3 * H_];
    float cv = sigf(gf) * cNb[(long)b * H_ + j] + sigf(gi) * tanhf(gg);
    hdec[idx] = f2bf(sigf(go) * tanhf(cv));
}

__global__ __launch_bounds__(256) void k_mlp3(const float* __restrict__ z2,
                                              const float* __restrict__ W3,
                                              const float* __restrict__ b3,
                                              float* __restrict__ out) {
    int wave = threadIdx.x >> 6, lane = threadIdx.x & 63;
    int m = blockIdx.x * 4 + wave;
    const float* zr = z2 + (long)m * P2_;
    float s = zr[lane] * W3[lane] + zr[64 + lane] * W3[64 + lane];
    #pragma unroll
    for (int off = 32; off > 0; off >>= 1) s += __shfl_down(s, off);
    if (lane == 0) out[m] = sigf(s + b3[0]);
}

extern "C" void kernel_launch(void* const* d_in, const int* in_sizes, int n_in,
                              void* d_out, int out_size, void* d_ws, size_t ws_size,
                              hipStream_t stream)
{
    const int*   x    = (const int*)d_in[0];
    const float* emb  = (const float*)d_in[1];
    const float* W_ih = (const float*)d_in[2];
    const float* W_hh = (const float*)d_in[3];
    const float* b_ih = (const float*)d_in[4];
    const float* b_hh = (const float*)d_in[5];
    const float* W1   = (const float*)d_in[6];
    const float* b1   = (const float*)d_in[7];
    const float* W2   = (const float*)d_in[8];
    const float* b2   = (const float*)d_in[9];
    const float* W3   = (const float*)d_in[10];
    const float* b3   = (const float*)d_in[11];
    float* out = (float*)d_out;

    float* ws = (float*)d_ws;
    ushort* ebf  = (ushort*)ws;                 // B*S*E bf16 (3,276,800 f)
    float* Xg    = ws + 3276800;                // 26,214,400 f
    float* bsum  = Xg + 26214400;               // 1024
    float* hN    = bsum + 1024;                 // 65,536
    float* cN    = hN + 65536;                  // 65,536
    float* hhdec = cN + 65536;                  // 262,144
    uint*  WPu   = (uint*)(hhdec + 262144);     // 131,072 uints (512 KB)
    ushort* Wihb = (ushort*)(WPu + 131072);     // 131,072 ush
    ushort* W1T  = Wihb + 131072;               // 131,072 ush
    ushort* W2T  = W1T + 131072;                // 65,536 ush
    // reuse (stream-ordered):
    ushort* hdec_bf = ebf;
    ushort* z1b  = (ushort*)Xg;
    float*  z2   = Xg + 6553600;

    k_bsum<<<4, 256, 0, stream>>>(b_ih, b_hh, bsum);
    k_prep_wp<<<dim3(8, 32), 256, 0, stream>>>(W_hh, WPu);
    k_tr_bf16<<<dim3(16, 8),  256, 0, stream>>>(W1, W1T, H_, P1_);
    k_tr_bf16<<<dim3(4, 16),  256, 0, stream>>>(W2, W2T, P1_, P2_);
    k_cvt_bf16<<<512, 256, 0, stream>>>(W_ih, Wihb, G4 * E_);
    k_gather<<<B_ * S_, 128, 0, stream>>>(x, emb, ebf);

    // Xg = e_hist @ W_ih^T + bsum
    k_gemm_mfma<0, 0><<<dim3(G4 / 128, (B_ * T_) / 128), 256, 0, stream>>>(
        ebf, T_, (long)S_ * E_, (long)E_, Wihb, bsum, nullptr, 1,
        Xg, G4, E_);

    // persistent scan: W resident in LDS+VGPR, 12 rows streamed
    size_t scan_smem = (size_t)NL_ * 4096 + G4 * sizeof(float) + 128 * sizeof(uint);
    k_lstm_scan<<<B_, 1024, scan_smem, stream>>>(Xg, WPu, hN, cN);

    // hhdec = hN @ W_hh^T + bsum (fp32, tiny)
    k_gemm<1, 0><<<dim3(G4 / 128, B_ / 64), 256, 0, stream>>>(
        hN, B_, 0L, (long)H_, W_hh, bsum, nullptr, 1,
        hhdec, B_, G4, H_);

    // Gdec = e_tgt @ W_ih^T + hhdec[b]
    k_gemm_mfma<0, 0><<<dim3(G4 / 128, (B_ * T_) / 128), 256, 0, stream>>>(
        ebf + T_ * E_, T_, (long)S_ * E_, (long)E_, Wihb, nullptr, hhdec, T_,
        Xg, G4, E_);

    // decode cell -> hdec_bf
    k_dec_cell<<<(B_ * T_ * H_) / 256, 256, 0, stream>>>(Xg, cN, hdec_bf);

    // z1 = relu(hdec @ W1 + b1) -> bf16
    k_gemm_mfma<1, 1><<<dim3(P1_ / 128, (B_ * T_) / 128), 256, 0, stream>>>(
        hdec_bf, B_ * T_, 0L, (long)H_, W1T, b1, nullptr, 1,
        z1b, P1_, H_);

    // z2 = relu(z1 @ W2 + b2) -> f32
    k_gemm_mfma<1, 0><<<dim3(P2_ / 128, (B_ * T_) / 128), 256, 0, stream>>>(
        z1b, B_ * T_, 0L, (long)P1_, W2T, b2, nullptr, 1,
        z2, P2_, P1_);

    // out = sigmoid(z2 . W3 + b3)
    k_mlp3<<<(B_ * T_) / 4, 256, 0, stream>>>(z2, W3, b3, out);
}